// Round 10
// baseline (597.078 us; speedup 1.0000x reference)
//
#include <hip/hip_runtime.h>
#include <hip/hip_fp16.h>
#include <math.h>

#define NN 100000
#define ICH 128
#define OCH 40
#define NE 3200000
#define BSH 8                          // scan bucket = node >> 8 (256 nodes)
#define BNODES 256
#define NB 391                         // ceil(100000/256)
#define YSTRIDE 40                     // fp8 row: 40 B packed -> whole y array 4.0 MB ~ L2-resident
#define YU2 (YSTRIDE / 8)              // 5 uint2 per row
#define XWBLK 1563                     // ceil(NN/64) blocks of 128 threads (2 waves x 32 rows)

typedef __attribute__((ext_vector_type(2))) float floatx2;
typedef __attribute__((ext_vector_type(4))) float floatx4;  // native vec for __builtin_nontemporal_store
typedef __attribute__((ext_vector_type(8))) short bf16x8;   // MFMA A/B fragment (4 VGPRs)

// v_cvt_pk_bf16_f32: pack 2 f32 -> 2 bf16 in one u32 (lo16 = src0), RNE. No builtin on gfx950.
__device__ __forceinline__ unsigned int pk_bf16(float a, float b) {
    unsigned int r;
    asm("v_cvt_pk_bf16_f32 %0, %1, %2" : "=v"(r) : "v"(a), "v"(b));
    return r;
}

// decode 8 fp8 (uint2) -> acc[8] +=
__device__ __forceinline__ void acc_fp8x8(const uint2 u, float* acc) {
    floatx2 p0 = __builtin_amdgcn_cvt_pk_f32_fp8((int)u.x, false);
    floatx2 p1 = __builtin_amdgcn_cvt_pk_f32_fp8((int)u.x, true);
    floatx2 p2 = __builtin_amdgcn_cvt_pk_f32_fp8((int)u.y, false);
    floatx2 p3 = __builtin_amdgcn_cvt_pk_f32_fp8((int)u.y, true);
    acc[0] += p0.x; acc[1] += p0.y; acc[2] += p1.x; acc[3] += p1.y;
    acc[4] += p2.x; acc[5] += p2.y; acc[6] += p3.x; acc[7] += p3.y;
}

// encode 8 f32 -> uint2 of fp8
__device__ __forceinline__ uint2 pack_fp8x8(const float* v) {
    int lo = 0, hi = 0;
    lo = __builtin_amdgcn_cvt_pk_fp8_f32(v[0], v[1], lo, false);
    lo = __builtin_amdgcn_cvt_pk_fp8_f32(v[2], v[3], lo, true);
    hi = __builtin_amdgcn_cvt_pk_fp8_f32(v[4], v[5], hi, false);
    hi = __builtin_amdgcn_cvt_pk_fp8_f32(v[6], v[7], hi, true);
    return make_uint2((unsigned int)lo, (unsigned int)hi);
}

// gather-accumulate over one CSR row, software-pipelined GATHERS (verified optimum:
// 5 lanes x 8B, 8-deep, VGPR ~36 -> occupancy in the request-throughput-bound regime)
__device__ __forceinline__ void row_gather(const int* __restrict__ csr, int kb, int ke, int q,
                                           const uint2* __restrict__ base, float* acc) {
    int k = kb;
    if (k + 8 <= ke) {
        int s[8];
        uint2 v[8];
#pragma unroll
        for (int j = 0; j < 8; ++j) s[j] = csr[k + j];
#pragma unroll
        for (int j = 0; j < 8; ++j) v[j] = base[(size_t)s[j] * YU2 + q];
        k += 8;
        for (; k + 8 <= ke; k += 8) {
            int s2[8];
            uint2 w[8];
#pragma unroll
            for (int j = 0; j < 8; ++j) s2[j] = csr[k + j];
#pragma unroll
            for (int j = 0; j < 8; ++j) w[j] = base[(size_t)s2[j] * YU2 + q];  // in flight during acc below
#pragma unroll
            for (int j = 0; j < 8; ++j) acc_fp8x8(v[j], acc);
#pragma unroll
            for (int j = 0; j < 8; ++j) v[j] = w[j];
        }
#pragma unroll
        for (int j = 0; j < 8; ++j) acc_fp8x8(v[j], acc);
    }
    for (; k < ke; ++k) acc_fp8x8(base[(size_t)csr[k] * YU2 + q], acc);
}

// ---- phase 1: per-node in-degree via global atomics; block 0 also shuffles W ----
// wbf layout: [hs(2)][s(4)][n(3)][lane(64)] x short8 ; entry e holds W[s*32+(lane>>4)*8+j][n*16+(lane&15)]
__global__ __launch_bounds__(256) void k_deg(const int* __restrict__ ei, int* __restrict__ deg,
                                             const float* __restrict__ W, unsigned int* __restrict__ wbf) {
    int e0 = (blockIdx.x * 256 + threadIdx.x) * 4;       // NE % 4 == 0, grid covers exactly
    if (e0 < NE) {
        int4 d = *(const int4*)(ei + NE + e0);
        atomicAdd(&deg[d.x], 1);
        atomicAdd(&deg[d.y], 1);
        atomicAdd(&deg[d.z], 1);
        atomicAdd(&deg[d.w], 1);
    }
    if (blockIdx.x == 0) {
        int t = threadIdx.x;
        for (int e = t; e < 1536; e += 256) {
            int hs = e / 768;
            int rem = e - hs * 768;
            int ss = rem / 192;
            int rem2 = rem - ss * 192;
            int n = rem2 >> 6;
            int lane = rem2 & 63;
            int kbase = ss * 32 + (lane >> 4) * 8;
            int col = n * 16 + (lane & 15);
            unsigned int u4[4];
#pragma unroll
            for (int p = 0; p < 4; ++p) {
                float f0 = (col < OCH) ? W[(size_t)(kbase + 2 * p) * OCH + col] : 0.f;
                float f1 = (col < OCH) ? W[(size_t)(kbase + 2 * p + 1) * OCH + col] : 0.f;
                unsigned int h = pk_bf16(f0, f1);
                if (hs == 0) {
                    u4[p] = h;
                } else {
                    float l0 = f0 - __uint_as_float(h << 16);
                    float l1 = f1 - __uint_as_float(h & 0xFFFF0000u);
                    u4[p] = pk_bf16(l0, l1);
                }
            }
            ((uint4*)wbf)[e] = make_uint4(u4[0], u4[1], u4[2], u4[3]);
        }
    }
}

// ---- phase 2a: per-bucket degree sums ----
__global__ __launch_bounds__(256) void k_bsum(const int* __restrict__ deg, int* __restrict__ bsum) {
    __shared__ int s[256];
    int b = blockIdx.x, t = threadIdx.x;
    int node = (b << BSH) + t;
    s[t] = (node < NN) ? deg[node] : 0;
    __syncthreads();
    for (int off = 128; off > 0; off >>= 1) {
        if (t < off) s[t] += s[t + off];
        __syncthreads();
    }
    if (t == 0) bsum[b] = s[0];
}

// ---- phase 2b: rowptr/cur/dis from bucket sums (self-computed cbase, L2-hot bsum) ----
__global__ __launch_bounds__(256) void k_rowptr(const int* __restrict__ deg, const int* __restrict__ bsum,
                                                int* __restrict__ rowptr, int* __restrict__ cur,
                                                float* __restrict__ dis) {
    __shared__ int sred[256], ps[BNODES];
    int b = blockIdx.x, t = threadIdx.x;
    int part = 0;
    for (int j = t; j < b; j += 256) part += bsum[j];
    sred[t] = part;
    __syncthreads();
    for (int off = 128; off > 0; off >>= 1) {
        if (t < off) sred[t] += sred[t + off];
        __syncthreads();
    }
    int cbase = sred[0];
    int node = (b << BSH) + t;
    int d = (node < NN) ? deg[node] : 0;
    ps[t] = d;
    __syncthreads();
    for (int off = 1; off < BNODES; off <<= 1) {
        int u = (t >= off) ? ps[t - off] : 0;
        __syncthreads();
        ps[t] += u;
        __syncthreads();
    }
    if (node < NN) {
        int excl = cbase + ps[t] - d;
        rowptr[node] = excl;
        cur[node] = excl;
        dis[node] = rsqrtf((float)d + 1.0f);
    }
    if (b == 0 && t == 0) rowptr[NN] = NE;
}

// ---- phase 3: scatter edges into CSR via returning atomics ----
__global__ __launch_bounds__(256) void k_scat(const int* __restrict__ ei, int* __restrict__ cur,
                                              int* __restrict__ csr) {
    int e0 = (blockIdx.x * 256 + threadIdx.x) * 4;
    if (e0 >= NE) return;
    int4 s = *(const int4*)(ei + e0);
    int4 d = *(const int4*)(ei + NE + e0);
    int p0 = atomicAdd(&cur[d.x], 1);
    int p1 = atomicAdd(&cur[d.y], 1);
    int p2 = atomicAdd(&cur[d.z], 1);
    int p3 = atomicAdd(&cur[d.w], 1);
    csr[p0] = s.x;
    csr[p1] = s.y;
    csr[p2] = s.z;
    csr[p3] = s.w;
}

// ---- y0 = fp8( dis * (x @ W) ) via MFMA bf16 with 3-term split (f32-accurate) ----
__global__ __launch_bounds__(128) void k_xw(const float* __restrict__ x, const unsigned int* __restrict__ wbf,
                                            const float* __restrict__ dis, unsigned char* __restrict__ y0) {
    int t = threadIdx.x;
    int wid = t >> 6, lane = t & 63;
    const bf16x8* wf = (const bf16x8*)wbf;
    bf16x8 whi[4][3], wlo[4][3];
#pragma unroll
    for (int s = 0; s < 4; ++s)
#pragma unroll
        for (int n = 0; n < 3; ++n) {
            whi[s][n] = wf[(s * 3 + n) * 64 + lane];
            wlo[s][n] = wf[768 + (s * 3 + n) * 64 + lane];
        }
    int rbase = blockIdx.x * 64 + wid * 32;
#pragma unroll
    for (int tt = 0; tt < 2; ++tt) {
        int r0 = rbase + tt * 16;
        int rowa = r0 + (lane & 15);
        int rowc = min(rowa, NN - 1);                    // clamp for loads
        int kb = (lane >> 4) * 8;
        const float4* xp = (const float4*)(x + (size_t)rowc * ICH + kb);
        float4 xa[4][2];
#pragma unroll
        for (int s = 0; s < 4; ++s) {
            xa[s][0] = xp[s * 8];
            xa[s][1] = xp[s * 8 + 1];
        }
        floatx4 acc[3] = {{0.f, 0.f, 0.f, 0.f}, {0.f, 0.f, 0.f, 0.f}, {0.f, 0.f, 0.f, 0.f}};
#pragma unroll
        for (int s = 0; s < 4; ++s) {
            float f[8] = {xa[s][0].x, xa[s][0].y, xa[s][0].z, xa[s][0].w,
                          xa[s][1].x, xa[s][1].y, xa[s][1].z, xa[s][1].w};
            union { unsigned int u[4]; bf16x8 v; } ah, al;
#pragma unroll
            for (int p = 0; p < 4; ++p) {
                unsigned int h = pk_bf16(f[2 * p], f[2 * p + 1]);
                ah.u[p] = h;
                float l0 = f[2 * p] - __uint_as_float(h << 16);
                float l1 = f[2 * p + 1] - __uint_as_float(h & 0xFFFF0000u);
                al.u[p] = pk_bf16(l0, l1);
            }
#pragma unroll
            for (int n = 0; n < 3; ++n) {
                acc[n] = __builtin_amdgcn_mfma_f32_16x16x32_bf16(ah.v, whi[s][n], acc[n], 0, 0, 0);
                acc[n] = __builtin_amdgcn_mfma_f32_16x16x32_bf16(al.v, whi[s][n], acc[n], 0, 0, 0);
                acc[n] = __builtin_amdgcn_mfma_f32_16x16x32_bf16(ah.v, wlo[s][n], acc[n], 0, 0, 0);
            }
        }
        int rc0 = r0 + (lane >> 4) * 4;
        float dd[4];
#pragma unroll
        for (int r = 0; r < 4; ++r) dd[r] = (rc0 + r < NN) ? dis[rc0 + r] : 0.f;
#pragma unroll
        for (int n = 0; n < 3; ++n) {
            int col = n * 16 + (lane & 15);
            if (col < OCH) {
#pragma unroll
                for (int r = 0; r < 4; ++r) {
                    int row = rc0 + r;
                    if (row < NN) {
                        float val = acc[n][r] * dd[r];
                        int p8 = __builtin_amdgcn_cvt_pk_fp8_f32(val, val, 0, false);
                        y0[(size_t)row * YSTRIDE + col] = (unsigned char)(p8 & 0xFF);
                    }
                }
            }
        }
    }
}

// ---- hop 1: y1[i] = fp8( dis[i]^2 * (y0[i] + sum_in y0[src]) ) ----
__global__ __launch_bounds__(256) void k_hop1(const int* __restrict__ rowptr, const int* __restrict__ csr,
                                              const float* __restrict__ dis, const unsigned char* __restrict__ y0,
                                              unsigned char* __restrict__ y1) {
    int g = blockIdx.x * 256 + threadIdx.x;
    if (g >= NN * 5) return;
    int i = g / 5, q = g - 5 * i;
    const uint2* base = (const uint2*)y0;  // YU2=5 uint2 per 40 B row
    float acc[8];
#pragma unroll
    for (int j = 0; j < 8; ++j) acc[j] = 0.f;
    acc_fp8x8(base[(size_t)i * YU2 + q], acc);
    row_gather(csr, rowptr[i], rowptr[i + 1], q, base, acc);
    float d = dis[i], d2 = d * d;
#pragma unroll
    for (int j = 0; j < 8; ++j) acc[j] *= d2;
    ((uint2*)y1)[(size_t)i * YU2 + q] = pack_fp8x8(acc);
}

// ---- hop 2 gather + bias + log_softmax, fused; 64 nodes/block, 5 lanes/node ----
__global__ __launch_bounds__(320) void k_hop2f(const int* __restrict__ rowptr, const int* __restrict__ csr,
                                               const float* __restrict__ dis, const unsigned char* __restrict__ y1,
                                               const float* __restrict__ b, float* __restrict__ out) {
    __shared__ float red[64][5];
    int tid = threadIdx.x;
    int lg = tid / 5;
    int q = tid - 5 * lg;
    int g = blockIdx.x * 64 + lg;
    bool active = (g < NN);
    float l[8];
    if (active) {
        const uint2* base = (const uint2*)y1;
        float acc[8];
#pragma unroll
        for (int j = 0; j < 8; ++j) acc[j] = 0.f;
        acc_fp8x8(base[(size_t)g * YU2 + q], acc);
        row_gather(csr, rowptr[g], rowptr[g + 1], q, base, acc);
        float d = dis[g];
#pragma unroll
        for (int j = 0; j < 8; ++j) l[j] = d * acc[j] + b[8 * q + j];
    } else {
#pragma unroll
        for (int j = 0; j < 8; ++j) l[j] = -1e30f;
    }
    float m8 = l[0];
#pragma unroll
    for (int j = 1; j < 8; ++j) m8 = fmaxf(m8, l[j]);
    red[lg][q] = m8;
    __syncthreads();
    float gm = red[lg][0];
#pragma unroll
    for (int j = 1; j < 5; ++j) gm = fmaxf(gm, red[lg][j]);
    __syncthreads();
    float s8 = 0.f;
#pragma unroll
    for (int j = 0; j < 8; ++j) s8 += __expf(l[j] - gm);
    red[lg][q] = s8;
    __syncthreads();
    float gs = red[lg][0];
#pragma unroll
    for (int j = 1; j < 5; ++j) gs += red[lg][j];
    float ls = __logf(gs) + gm;
    if (active) {
        floatx4* orow = (floatx4*)(out + (size_t)g * OCH + 8 * q);
        floatx4 o0 = {l[0] - ls, l[1] - ls, l[2] - ls, l[3] - ls};
        floatx4 o1 = {l[4] - ls, l[5] - ls, l[6] - ls, l[7] - ls};
        __builtin_nontemporal_store(o0, orow);
        __builtin_nontemporal_store(o1, orow + 1);
    }
}

extern "C" void kernel_launch(void* const* d_in, const int* in_sizes, int n_in,
                              void* d_out, int out_size, void* d_ws, size_t ws_size,
                              hipStream_t stream) {
    const float* x  = (const float*)d_in[0];
    const int*   ei = (const int*)d_in[1];   // (2, E) int32; [0]=src, [1]=dst
    const float* W  = (const float*)d_in[2];
    const float* b  = (const float*)d_in[3];
    float* out = (float*)d_out;

    char* ws = (char*)d_ws;
    int*           rowptr = (int*)(ws + 0);              // NN+1 ints -> [0, 409600)
    float*         dis    = (float*)(ws + 409600);       // NN floats -> ends 809600
    int*           deg    = (int*)(ws + 819200);         // NN ints -> ends 1219200
    int*           cur    = (int*)(ws + 1228800);        // NN ints -> ends 1628800
    int*           bsum   = (int*)(ws + 1630208);        // NB ints
    unsigned int*  wbf    = (unsigned int*)(ws + 1638400); // 1536 x 16 B -> ends 1662976
    unsigned char* y0     = (unsigned char*)(ws + 1703936); // 4.0 MB
    unsigned char* y1     = (unsigned char*)(ws + 5709824); // 4.0 MB
    int*           csr    = (int*)(ws + 9715712);        // NE ints (12.8 MB) -> total ~22.5 MB

    hipMemsetAsync(deg, 0, NN * sizeof(int), stream);
    k_deg<<<(NE / 4 + 255) / 256, 256, 0, stream>>>(ei, deg, W, wbf);
    k_bsum<<<NB, 256, 0, stream>>>(deg, bsum);
    k_rowptr<<<NB, 256, 0, stream>>>(deg, bsum, rowptr, cur, dis);
    k_scat<<<(NE / 4 + 255) / 256, 256, 0, stream>>>(ei, cur, csr);
    k_xw<<<XWBLK, 128, 0, stream>>>(x, wbf, dis, y0);
    k_hop1<<<(NN * 5 + 255) / 256, 256, 0, stream>>>(rowptr, csr, dis, y0, y1);
    k_hop2f<<<(NN + 63) / 64, 320, 0, stream>>>(rowptr, csr, dis, y1, b, out);
}

// Round 11
// 242.798 us; speedup vs baseline: 2.4592x; 2.4592x over previous
//
#include <hip/hip_runtime.h>
#include <hip/hip_fp16.h>
#include <math.h>

#define NN 100000
#define ICH 128
#define OCH 40
#define NE 3200000
#define BSH 8                          // bucket = dst >> 8 (256 nodes/bucket)
#define BNODES 256
#define BMASK 255
#define NB 391                         // ceil(100000/256)
#define CAP 9216                       // per-bucket capacity (mean 8192, sigma ~91)
#define TILE 4096
#define NBIN ((NE + TILE - 1) / TILE)  // 782
#define YSTRIDE 40                     // fp8 row: 40 B packed -> whole y array 4.0 MB ~ L2-resident
#define YU2 (YSTRIDE / 8)              // 5 uint2 per row
#define XWBLK 1563                     // ceil(NN/64) blocks of 128 threads (2 waves x 32 rows)
#define HOPNPB 48                      // hop kernels: 4 waves x 12 nodes (5 lanes/node, lanes 0-59)
#define HOPGRID ((NN + HOPNPB - 1) / HOPNPB)  // 2084

typedef __attribute__((ext_vector_type(2))) float floatx2;
typedef __attribute__((ext_vector_type(4))) float floatx4;  // native vec for __builtin_nontemporal_store
typedef __attribute__((ext_vector_type(8))) short bf16x8;   // MFMA A/B fragment (4 VGPRs)

// v_cvt_pk_bf16_f32: pack 2 f32 -> 2 bf16 in one u32 (lo16 = src0), RNE. No builtin on gfx950.
__device__ __forceinline__ unsigned int pk_bf16(float a, float b) {
    unsigned int r;
    asm("v_cvt_pk_bf16_f32 %0, %1, %2" : "=v"(r) : "v"(a), "v"(b));
    return r;
}

// decode 8 fp8 (uint2) -> acc[8] +=
__device__ __forceinline__ void acc_fp8x8(const uint2 u, float* acc) {
    floatx2 p0 = __builtin_amdgcn_cvt_pk_f32_fp8((int)u.x, false);
    floatx2 p1 = __builtin_amdgcn_cvt_pk_f32_fp8((int)u.x, true);
    floatx2 p2 = __builtin_amdgcn_cvt_pk_f32_fp8((int)u.y, false);
    floatx2 p3 = __builtin_amdgcn_cvt_pk_f32_fp8((int)u.y, true);
    acc[0] += p0.x; acc[1] += p0.y; acc[2] += p1.x; acc[3] += p1.y;
    acc[4] += p2.x; acc[5] += p2.y; acc[6] += p3.x; acc[7] += p3.y;
}

// encode 8 f32 -> uint2 of fp8
__device__ __forceinline__ uint2 pack_fp8x8(const float* v) {
    int lo = 0, hi = 0;
    lo = __builtin_amdgcn_cvt_pk_fp8_f32(v[0], v[1], lo, false);
    lo = __builtin_amdgcn_cvt_pk_fp8_f32(v[2], v[3], lo, true);
    hi = __builtin_amdgcn_cvt_pk_fp8_f32(v[4], v[5], hi, false);
    hi = __builtin_amdgcn_cvt_pk_fp8_f32(v[6], v[7], hi, true);
    return make_uint2((unsigned int)lo, (unsigned int)hi);
}

// load 8 csr indices for a 5-lane node group: lanes q<4 load uint2 (one VMEM instr for the
// group instead of 8), then redistribute via ds_bpermute (LDS pipe, idle here).
// base = wave-lane index of the group's q=0 lane; group is wave-aligned and row-uniform.
__device__ __forceinline__ void grp_csr8(const int* __restrict__ csr, int k, int q, int base, int* s) {
    uint2 c = make_uint2(0u, 0u);
    if (q < 4) c = *(const uint2*)(csr + k + 2 * q);
#pragma unroll
    for (int j = 0; j < 8; ++j)
        s[j] = __shfl((j & 1) ? (int)c.y : (int)c.x, base + (j >> 1), 64);
}

// gather-accumulate over one CSR row: wave-local group csr sharing + 8-deep gather pipeline
__device__ __forceinline__ void row_gather(const int* __restrict__ csr, int kb, int ke, int q, int base,
                                           const uint2* __restrict__ yb, float* acc) {
    int k = kb;
    if (k + 8 <= ke) {
        int s[8];
        uint2 v[8];
        grp_csr8(csr, k, q, base, s);
#pragma unroll
        for (int j = 0; j < 8; ++j) v[j] = yb[(size_t)s[j] * YU2 + q];
        k += 8;
        for (; k + 8 <= ke; k += 8) {
            int s2[8];
            uint2 w[8];
            grp_csr8(csr, k, q, base, s2);
#pragma unroll
            for (int j = 0; j < 8; ++j) w[j] = yb[(size_t)s2[j] * YU2 + q];  // in flight during acc below
#pragma unroll
            for (int j = 0; j < 8; ++j) acc_fp8x8(v[j], acc);
#pragma unroll
            for (int j = 0; j < 8; ++j) v[j] = w[j];
        }
#pragma unroll
        for (int j = 0; j < 8; ++j) acc_fp8x8(v[j], acc);
    }
    for (; k < ke; ++k) acc_fp8x8(yb[(size_t)csr[k] * YU2 + q], acc);
}

// ---- phase 1: bin edges by dst-bucket; block 0 additionally emits the W fragment shuffle ----
// wbf layout: [hs(2)][s(4)][n(3)][lane(64)] x short8 ; entry e holds W[s*32+(lane>>4)*8+j][n*16+(lane&15)]
__global__ __launch_bounds__(512) void k_bin(const int* __restrict__ ei, int* __restrict__ bcursor,
                                             unsigned int* __restrict__ packed,
                                             const float* __restrict__ W, unsigned int* __restrict__ wbf) {
    __shared__ unsigned int entries[TILE];
    __shared__ unsigned short bid[TILE];
    __shared__ int hist[512], base[512], gbase[512], cur[512];
    int t = threadIdx.x;
    int tile0 = blockIdx.x * TILE;
    int tcnt = min(TILE, NE - tile0);
    hist[t] = 0;
    __syncthreads();
    int src[8], dst[8];
#pragma unroll
    for (int i = 0; i < 8; ++i) {
        int l = t + i * 512;
        if (l < tcnt) {
            int e = tile0 + l;
            src[i] = ei[e];
            dst[i] = ei[NE + e];
            atomicAdd(&hist[dst[i] >> BSH], 1);
        } else dst[i] = -1;
    }
    __syncthreads();
    int own = hist[t];
    base[t] = own;
    __syncthreads();
    for (int off = 1; off < 512; off <<= 1) {
        int v = (t >= off) ? base[t - off] : 0;
        __syncthreads();
        base[t] += v;
        __syncthreads();
    }
    int excl = base[t] - own;
    __syncthreads();
    base[t] = excl;
    cur[t] = excl;
    if (t < NB && own > 0) gbase[t] = atomicAdd(&bcursor[t], own);
    __syncthreads();
#pragma unroll
    for (int i = 0; i < 8; ++i) {
        if (dst[i] >= 0) {
            int bb = dst[i] >> BSH;
            int pos = atomicAdd(&cur[bb], 1);
            entries[pos] = ((unsigned int)(dst[i] & BMASK) << 17) | (unsigned int)src[i];
            bid[pos] = (unsigned short)bb;
        }
    }
    __syncthreads();
    for (int l = t; l < tcnt; l += 512) {
        int bb = bid[l];
        packed[(size_t)bb * CAP + gbase[bb] + (l - base[bb])] = entries[l];
    }
    // one-time W shuffle (hi+lo bf16 split), done by block 0's tail, hidden under other blocks
    if (blockIdx.x == 0) {
        for (int e = t; e < 1536; e += 512) {
            int hs = e / 768;
            int rem = e - hs * 768;
            int ss = rem / 192;
            int rem2 = rem - ss * 192;
            int n = rem2 >> 6;
            int lane = rem2 & 63;
            int kbase = ss * 32 + (lane >> 4) * 8;
            int col = n * 16 + (lane & 15);
            unsigned int u4[4];
#pragma unroll
            for (int p = 0; p < 4; ++p) {
                float f0 = (col < OCH) ? W[(size_t)(kbase + 2 * p) * OCH + col] : 0.f;
                float f1 = (col < OCH) ? W[(size_t)(kbase + 2 * p + 1) * OCH + col] : 0.f;
                unsigned int h = pk_bf16(f0, f1);
                if (hs == 0) {
                    u4[p] = h;
                } else {
                    float l0 = f0 - __uint_as_float(h << 16);
                    float l1 = f1 - __uint_as_float(h & 0xFFFF0000u);
                    u4[p] = pk_bf16(l0, l1);
                }
            }
            ((uint4*)wbf)[e] = make_uint4(u4[0], u4[1], u4[2], u4[3]);
        }
    }
}

// ---- phase 2: per-bucket CSR build; self-computed cbase (no k_bscan), no LDS edge staging ----
__global__ __launch_bounds__(512) void k_csr(const int* __restrict__ bcursor,
                                             const unsigned int* __restrict__ packed,
                                             int* __restrict__ rowptr, float* __restrict__ dis,
                                             int* __restrict__ csr) {
    __shared__ int hist[BNODES], cur[BNODES], ps[BNODES], sred[512];
    int b = blockIdx.x;
    int t = threadIdx.x;
    // cbase = sum_{j<b} bcursor[j]  (bcursor is 1.5 KB, L2-hot)
    int part = 0;
    for (int j = t; j < b; j += 512) part += bcursor[j];
    sred[t] = part;
    if (t < BNODES) hist[t] = 0;
    __syncthreads();
    for (int off = 256; off > 0; off >>= 1) {
        if (t < off) sred[t] += sred[t + off];
        __syncthreads();
    }
    int cbase = sred[0];
    int cnt = bcursor[b];
    int node0 = b << BSH;
    int nn = min(BNODES, NN - node0);
    const unsigned int* pk = packed + (size_t)b * CAP;
    for (int l = t; l < cnt; l += 512) atomicAdd(&hist[pk[l] >> 17], 1);
    __syncthreads();
    if (t < BNODES) ps[t] = hist[t];
    __syncthreads();
    for (int off = 1; off < BNODES; off <<= 1) {
        int u = (t >= off && t < BNODES) ? ps[t - off] : 0;
        __syncthreads();
        if (t < BNODES) ps[t] += u;
        __syncthreads();
    }
    if (t < BNODES) {
        int excl = ps[t] - hist[t];
        cur[t] = excl;
        if (t < nn) {
            rowptr[node0 + t] = cbase + excl;
            dis[node0 + t] = rsqrtf((float)hist[t] + 1.0f);
        }
    }
    if (b == 0 && t == 0) rowptr[NN] = NE;
    __syncthreads();
    for (int l = t; l < cnt; l += 512) {
        unsigned int e = pk[l];               // second read: bucket slab is 32 KB, L2-resident
        int pos = atomicAdd(&cur[e >> 17], 1);
        csr[cbase + pos] = (int)(e & 0x1FFFF);
    }
}

// ---- y0 = fp8( dis * (x @ W) ) via MFMA bf16 with 3-term split (f32-accurate) ----
__global__ __launch_bounds__(128) void k_xw(const float* __restrict__ x, const unsigned int* __restrict__ wbf,
                                            const float* __restrict__ dis, unsigned char* __restrict__ y0) {
    int t = threadIdx.x;
    int wid = t >> 6, lane = t & 63;
    const bf16x8* wf = (const bf16x8*)wbf;
    bf16x8 whi[4][3], wlo[4][3];
#pragma unroll
    for (int s = 0; s < 4; ++s)
#pragma unroll
        for (int n = 0; n < 3; ++n) {
            whi[s][n] = wf[(s * 3 + n) * 64 + lane];
            wlo[s][n] = wf[768 + (s * 3 + n) * 64 + lane];
        }
    int rbase = blockIdx.x * 64 + wid * 32;
#pragma unroll
    for (int tt = 0; tt < 2; ++tt) {
        int r0 = rbase + tt * 16;
        int rowa = r0 + (lane & 15);
        int rowc = min(rowa, NN - 1);                    // clamp for loads
        int kb = (lane >> 4) * 8;
        const float4* xp = (const float4*)(x + (size_t)rowc * ICH + kb);
        float4 xa[4][2];
#pragma unroll
        for (int s = 0; s < 4; ++s) {
            xa[s][0] = xp[s * 8];
            xa[s][1] = xp[s * 8 + 1];
        }
        floatx4 acc[3] = {{0.f, 0.f, 0.f, 0.f}, {0.f, 0.f, 0.f, 0.f}, {0.f, 0.f, 0.f, 0.f}};
#pragma unroll
        for (int s = 0; s < 4; ++s) {
            float f[8] = {xa[s][0].x, xa[s][0].y, xa[s][0].z, xa[s][0].w,
                          xa[s][1].x, xa[s][1].y, xa[s][1].z, xa[s][1].w};
            union { unsigned int u[4]; bf16x8 v; } ah, al;
#pragma unroll
            for (int p = 0; p < 4; ++p) {
                unsigned int h = pk_bf16(f[2 * p], f[2 * p + 1]);
                ah.u[p] = h;
                float l0 = f[2 * p] - __uint_as_float(h << 16);
                float l1 = f[2 * p + 1] - __uint_as_float(h & 0xFFFF0000u);
                al.u[p] = pk_bf16(l0, l1);
            }
#pragma unroll
            for (int n = 0; n < 3; ++n) {
                acc[n] = __builtin_amdgcn_mfma_f32_16x16x32_bf16(ah.v, whi[s][n], acc[n], 0, 0, 0);
                acc[n] = __builtin_amdgcn_mfma_f32_16x16x32_bf16(al.v, whi[s][n], acc[n], 0, 0, 0);
                acc[n] = __builtin_amdgcn_mfma_f32_16x16x32_bf16(ah.v, wlo[s][n], acc[n], 0, 0, 0);
            }
        }
        int rc0 = r0 + (lane >> 4) * 4;
        float dd[4];
#pragma unroll
        for (int r = 0; r < 4; ++r) dd[r] = (rc0 + r < NN) ? dis[rc0 + r] : 0.f;
#pragma unroll
        for (int n = 0; n < 3; ++n) {
            int col = n * 16 + (lane & 15);
            if (col < OCH) {
#pragma unroll
                for (int r = 0; r < 4; ++r) {
                    int row = rc0 + r;
                    if (row < NN) {
                        float val = acc[n][r] * dd[r];
                        int p8 = __builtin_amdgcn_cvt_pk_fp8_f32(val, val, 0, false);
                        y0[(size_t)row * YSTRIDE + col] = (unsigned char)(p8 & 0xFF);
                    }
                }
            }
        }
    }
}

// ---- hop 1: y1[i] = fp8( dis[i]^2 * (y0[i] + sum_in y0[src]) ); wave-aligned 5-lane groups ----
__global__ __launch_bounds__(256) void k_hop1(const int* __restrict__ rowptr, const int* __restrict__ csr,
                                              const float* __restrict__ dis, const unsigned char* __restrict__ y0,
                                              unsigned char* __restrict__ y1) {
    int t = threadIdx.x;
    int wave = t >> 6, lane = t & 63;
    int grp = lane / 5, q = lane - 5 * grp;
    int i = blockIdx.x * HOPNPB + wave * 12 + grp;
    if (grp >= 12 || i >= NN) return;
    int base = lane - q;                                 // wave-lane of group's q=0
    const uint2* yb = (const uint2*)y0;
    float acc[8];
#pragma unroll
    for (int j = 0; j < 8; ++j) acc[j] = 0.f;
    acc_fp8x8(yb[(size_t)i * YU2 + q], acc);
    row_gather(csr, rowptr[i], rowptr[i + 1], q, base, yb, acc);
    float d = dis[i], d2 = d * d;
#pragma unroll
    for (int j = 0; j < 8; ++j) acc[j] *= d2;
    ((uint2*)y1)[(size_t)i * YU2 + q] = pack_fp8x8(acc);
}

// ---- hop 2 gather + bias + log_softmax, fused; wave-aligned groups, shfl-only reduction ----
__global__ __launch_bounds__(256) void k_hop2f(const int* __restrict__ rowptr, const int* __restrict__ csr,
                                               const float* __restrict__ dis, const unsigned char* __restrict__ y1,
                                               const float* __restrict__ b, float* __restrict__ out) {
    int t = threadIdx.x;
    int wave = t >> 6, lane = t & 63;
    int grp = lane / 5, q = lane - 5 * grp;
    int g = blockIdx.x * HOPNPB + wave * 12 + grp;
    if (grp >= 12 || g >= NN) return;
    int base = lane - q;
    const uint2* yb = (const uint2*)y1;
    float acc[8];
#pragma unroll
    for (int j = 0; j < 8; ++j) acc[j] = 0.f;
    acc_fp8x8(yb[(size_t)g * YU2 + q], acc);
    row_gather(csr, rowptr[g], rowptr[g + 1], q, base, yb, acc);
    float d = dis[g];
    float l[8];
#pragma unroll
    for (int j = 0; j < 8; ++j) l[j] = d * acc[j] + b[8 * q + j];
    float m8 = l[0];
#pragma unroll
    for (int j = 1; j < 8; ++j) m8 = fmaxf(m8, l[j]);
    float gm = m8;
#pragma unroll
    for (int j = 1; j < 5; ++j) gm = fmaxf(gm, __shfl(m8, base + j, 64));
    float s8 = 0.f;
#pragma unroll
    for (int j = 0; j < 8; ++j) s8 += __expf(l[j] - gm);
    float gs = s8;
#pragma unroll
    for (int j = 1; j < 5; ++j) gs += __shfl(s8, base + j, 64);
    float ls = __logf(gs) + gm;
    floatx4* orow = (floatx4*)(out + (size_t)g * OCH + 8 * q);
    floatx4 o0 = {l[0] - ls, l[1] - ls, l[2] - ls, l[3] - ls};
    floatx4 o1 = {l[4] - ls, l[5] - ls, l[6] - ls, l[7] - ls};
    __builtin_nontemporal_store(o0, orow);
    __builtin_nontemporal_store(o1, orow + 1);
}

extern "C" void kernel_launch(void* const* d_in, const int* in_sizes, int n_in,
                              void* d_out, int out_size, void* d_ws, size_t ws_size,
                              hipStream_t stream) {
    const float* x  = (const float*)d_in[0];
    const int*   ei = (const int*)d_in[1];   // (2, E) int32; [0]=src, [1]=dst
    const float* W  = (const float*)d_in[2];
    const float* b  = (const float*)d_in[3];
    float* out = (float*)d_out;

    char* ws = (char*)d_ws;
    int*           bcursor = (int*)(ws + 0);            // NB ints
    int*           rowptr  = (int*)(ws + 4096);         // NN+1 ints -> ends 404100
    float*         dis     = (float*)(ws + 409600);     // NN floats -> ends 809600
    unsigned int*  wbf     = (unsigned int*)(ws + 811008);   // 1536 x 16 B -> ends 835584
    unsigned int*  packed  = (unsigned int*)(ws + 843776);   // NB*CAP*4 = 14.41 MB (dead after k_csr)
    unsigned char* y0      = (unsigned char*)(ws + 843776);  // aliases packed, 4.0 MB
    unsigned char* y1      = (unsigned char*)(ws + 4849664); // aliases packed, 4.0 MB (ends 8849664)
    int*           csr     = (int*)(ws + 15261696);     // NE ints (12.8 MB) -> total ~28.06 MB

    hipMemsetAsync(bcursor, 0, NB * sizeof(int), stream);
    k_bin<<<NBIN, 512, 0, stream>>>(ei, bcursor, packed, W, wbf);
    k_csr<<<NB, 512, 0, stream>>>(bcursor, packed, rowptr, dis, csr);
    k_xw<<<XWBLK, 128, 0, stream>>>(x, wbf, dis, y0);
    k_hop1<<<HOPGRID, 256, 0, stream>>>(rowptr, csr, dis, y0, y1);
    k_hop2f<<<HOPGRID, 256, 0, stream>>>(rowptr, csr, dis, y1, b, out);
}

// Round 12
// 233.960 us; speedup vs baseline: 2.5521x; 1.0378x over previous
//
#include <hip/hip_runtime.h>
#include <hip/hip_fp16.h>
#include <math.h>

#define NN 100000
#define ICH 128
#define OCH 40
#define NE 3200000
#define BSH 8                          // bucket = dst >> 8 (256 nodes/bucket)
#define BNODES 256
#define BMASK 255
#define NB 391                         // ceil(100000/256)
#define CAP 9216                       // per-bucket capacity (mean 8192, sigma ~91)
#define TILE 4096
#define NBIN ((NE + TILE - 1) / TILE)  // 782
#define YSTRIDE 40                     // fp8 row: 40 B packed -> whole y array 4.0 MB ~ L2-resident
#define YU2 (YSTRIDE / 8)              // 5 uint2 per row
#define XWBLK 1563                     // ceil(NN/64) blocks of 128 threads (2 waves x 32 rows)
#define HOPNPB 48                      // hop kernels: 4 waves x 12 nodes (5 lanes/node, lanes 0-59)
#define HOPGRID ((NN + HOPNPB - 1) / HOPNPB)  // 2084

typedef __attribute__((ext_vector_type(2))) float floatx2;
typedef __attribute__((ext_vector_type(4))) float floatx4;  // native vec for __builtin_nontemporal_store
typedef __attribute__((ext_vector_type(8))) short bf16x8;   // MFMA A/B fragment (4 VGPRs)

// v_cvt_pk_bf16_f32: pack 2 f32 -> 2 bf16 in one u32 (lo16 = src0), RNE. No builtin on gfx950.
__device__ __forceinline__ unsigned int pk_bf16(float a, float b) {
    unsigned int r;
    asm("v_cvt_pk_bf16_f32 %0, %1, %2" : "=v"(r) : "v"(a), "v"(b));
    return r;
}

// decode 8 fp8 (uint2) -> acc[8] +=
__device__ __forceinline__ void acc_fp8x8(const uint2 u, float* acc) {
    floatx2 p0 = __builtin_amdgcn_cvt_pk_f32_fp8((int)u.x, false);
    floatx2 p1 = __builtin_amdgcn_cvt_pk_f32_fp8((int)u.x, true);
    floatx2 p2 = __builtin_amdgcn_cvt_pk_f32_fp8((int)u.y, false);
    floatx2 p3 = __builtin_amdgcn_cvt_pk_f32_fp8((int)u.y, true);
    acc[0] += p0.x; acc[1] += p0.y; acc[2] += p1.x; acc[3] += p1.y;
    acc[4] += p2.x; acc[5] += p2.y; acc[6] += p3.x; acc[7] += p3.y;
}

// encode 8 f32 -> uint2 of fp8
__device__ __forceinline__ uint2 pack_fp8x8(const float* v) {
    int lo = 0, hi = 0;
    lo = __builtin_amdgcn_cvt_pk_fp8_f32(v[0], v[1], lo, false);
    lo = __builtin_amdgcn_cvt_pk_fp8_f32(v[2], v[3], lo, true);
    hi = __builtin_amdgcn_cvt_pk_fp8_f32(v[4], v[5], hi, false);
    hi = __builtin_amdgcn_cvt_pk_fp8_f32(v[6], v[7], hi, true);
    return make_uint2((unsigned int)lo, (unsigned int)hi);
}

// load 8 csr indices for a 5-lane node group: lanes q<4 load uint2 (one VMEM instr for the
// group instead of 8), then redistribute via shfl. base = wave-lane of the group's q=0 lane.
__device__ __forceinline__ void grp_csr8(const int* __restrict__ csr, int k, int q, int base, int* s) {
    uint2 c = make_uint2(0u, 0u);
    if (q < 4) c = *(const uint2*)(csr + k + 2 * q);
#pragma unroll
    for (int j = 0; j < 8; ++j)
        s[j] = __shfl((j & 1) ? (int)c.y : (int)c.x, base + (j >> 1), 64);
}

// gather-accumulate over one CSR row: wave-local group csr sharing + 8-deep gather pipeline
__device__ __forceinline__ void row_gather(const int* __restrict__ csr, int kb, int ke, int q, int base,
                                           const uint2* __restrict__ yb, float* acc) {
    int k = kb;
    if (k + 8 <= ke) {
        int s[8];
        uint2 v[8];
        grp_csr8(csr, k, q, base, s);
#pragma unroll
        for (int j = 0; j < 8; ++j) v[j] = yb[(size_t)s[j] * YU2 + q];
        k += 8;
        for (; k + 8 <= ke; k += 8) {
            int s2[8];
            uint2 w[8];
            grp_csr8(csr, k, q, base, s2);
#pragma unroll
            for (int j = 0; j < 8; ++j) w[j] = yb[(size_t)s2[j] * YU2 + q];  // in flight during acc below
#pragma unroll
            for (int j = 0; j < 8; ++j) acc_fp8x8(v[j], acc);
#pragma unroll
            for (int j = 0; j < 8; ++j) v[j] = w[j];
        }
#pragma unroll
        for (int j = 0; j < 8; ++j) acc_fp8x8(v[j], acc);
    }
    for (; k < ke; ++k) acc_fp8x8(yb[(size_t)csr[k] * YU2 + q], acc);
}

// ---- phase 1: bin edges by dst-bucket; block 0 additionally emits the W fragment shuffle ----
// wbf layout: [hs(2)][s(4)][n(3)][lane(64)] x short8 ; entry e holds W[s*32+(lane>>4)*8+j][n*16+(lane&15)]
__global__ __launch_bounds__(512) void k_bin(const int* __restrict__ ei, int* __restrict__ bcursor,
                                             unsigned int* __restrict__ packed,
                                             const float* __restrict__ W, unsigned int* __restrict__ wbf) {
    __shared__ unsigned int entries[TILE];
    __shared__ unsigned short bid[TILE];
    __shared__ int hist[512], base[512], gbase[512], cur[512];
    int t = threadIdx.x;
    int tile0 = blockIdx.x * TILE;
    int tcnt = min(TILE, NE - tile0);
    hist[t] = 0;
    __syncthreads();
    int src[8], dst[8];
#pragma unroll
    for (int i = 0; i < 8; ++i) {
        int l = t + i * 512;
        if (l < tcnt) {
            int e = tile0 + l;
            src[i] = ei[e];
            dst[i] = ei[NE + e];
            atomicAdd(&hist[dst[i] >> BSH], 1);
        } else dst[i] = -1;
    }
    __syncthreads();
    int own = hist[t];
    base[t] = own;
    __syncthreads();
    for (int off = 1; off < 512; off <<= 1) {
        int v = (t >= off) ? base[t - off] : 0;
        __syncthreads();
        base[t] += v;
        __syncthreads();
    }
    int excl = base[t] - own;
    __syncthreads();
    base[t] = excl;
    cur[t] = excl;
    if (t < NB && own > 0) gbase[t] = atomicAdd(&bcursor[t], own);
    __syncthreads();
#pragma unroll
    for (int i = 0; i < 8; ++i) {
        if (dst[i] >= 0) {
            int bb = dst[i] >> BSH;
            int pos = atomicAdd(&cur[bb], 1);
            entries[pos] = ((unsigned int)(dst[i] & BMASK) << 17) | (unsigned int)src[i];
            bid[pos] = (unsigned short)bb;
        }
    }
    __syncthreads();
    for (int l = t; l < tcnt; l += 512) {
        int bb = bid[l];
        packed[(size_t)bb * CAP + gbase[bb] + (l - base[bb])] = entries[l];
    }
    // one-time W shuffle (hi+lo bf16 split), done by block 0's tail, hidden under other blocks
    if (blockIdx.x == 0) {
        for (int e = t; e < 1536; e += 512) {
            int hs = e / 768;
            int rem = e - hs * 768;
            int ss = rem / 192;
            int rem2 = rem - ss * 192;
            int n = rem2 >> 6;
            int lane = rem2 & 63;
            int kbase = ss * 32 + (lane >> 4) * 8;
            int col = n * 16 + (lane & 15);
            unsigned int u4[4];
#pragma unroll
            for (int p = 0; p < 4; ++p) {
                float f0 = (col < OCH) ? W[(size_t)(kbase + 2 * p) * OCH + col] : 0.f;
                float f1 = (col < OCH) ? W[(size_t)(kbase + 2 * p + 1) * OCH + col] : 0.f;
                unsigned int h = pk_bf16(f0, f1);
                if (hs == 0) {
                    u4[p] = h;
                } else {
                    float l0 = f0 - __uint_as_float(h << 16);
                    float l1 = f1 - __uint_as_float(h & 0xFFFF0000u);
                    u4[p] = pk_bf16(l0, l1);
                }
            }
            ((uint4*)wbf)[e] = make_uint4(u4[0], u4[1], u4[2], u4[3]);
        }
    }
}

// ---- phase 2: per-bucket CSR build; self-computed cbase (no k_bscan), no LDS edge staging ----
__global__ __launch_bounds__(512) void k_csr(const int* __restrict__ bcursor,
                                             const unsigned int* __restrict__ packed,
                                             int* __restrict__ rowptr, float* __restrict__ dis,
                                             int* __restrict__ csr) {
    __shared__ int hist[BNODES], cur[BNODES], ps[BNODES], sred[512];
    int b = blockIdx.x;
    int t = threadIdx.x;
    // cbase = sum_{j<b} bcursor[j]  (bcursor is 1.5 KB, L2-hot)
    int part = 0;
    for (int j = t; j < b; j += 512) part += bcursor[j];
    sred[t] = part;
    if (t < BNODES) hist[t] = 0;
    __syncthreads();
    for (int off = 256; off > 0; off >>= 1) {
        if (t < off) sred[t] += sred[t + off];
        __syncthreads();
    }
    int cbase = sred[0];
    int cnt = bcursor[b];
    int node0 = b << BSH;
    int nn = min(BNODES, NN - node0);
    const unsigned int* pk = packed + (size_t)b * CAP;
    for (int l = t; l < cnt; l += 512) atomicAdd(&hist[pk[l] >> 17], 1);
    __syncthreads();
    if (t < BNODES) ps[t] = hist[t];
    __syncthreads();
    for (int off = 1; off < BNODES; off <<= 1) {
        int u = (t >= off && t < BNODES) ? ps[t - off] : 0;
        __syncthreads();
        if (t < BNODES) ps[t] += u;
        __syncthreads();
    }
    if (t < BNODES) {
        int excl = ps[t] - hist[t];
        cur[t] = excl;
        if (t < nn) {
            rowptr[node0 + t] = cbase + excl;
            dis[node0 + t] = rsqrtf((float)hist[t] + 1.0f);
        }
    }
    if (b == 0 && t == 0) rowptr[NN] = NE;
    __syncthreads();
    for (int l = t; l < cnt; l += 512) {
        unsigned int e = pk[l];               // second read: bucket slab is 32 KB, L2-resident
        int pos = atomicAdd(&cur[e >> 17], 1);
        csr[cbase + pos] = (int)(e & 0x1FFFF);
    }
}

// ---- y0 = fp8( dis * (x @ W) ) via MFMA bf16 with 3-term split (f32-accurate) ----
__global__ __launch_bounds__(128) void k_xw(const float* __restrict__ x, const unsigned int* __restrict__ wbf,
                                            const float* __restrict__ dis, unsigned char* __restrict__ y0) {
    int t = threadIdx.x;
    int wid = t >> 6, lane = t & 63;
    const bf16x8* wf = (const bf16x8*)wbf;
    bf16x8 whi[4][3], wlo[4][3];
#pragma unroll
    for (int s = 0; s < 4; ++s)
#pragma unroll
        for (int n = 0; n < 3; ++n) {
            whi[s][n] = wf[(s * 3 + n) * 64 + lane];
            wlo[s][n] = wf[768 + (s * 3 + n) * 64 + lane];
        }
    int rbase = blockIdx.x * 64 + wid * 32;
#pragma unroll
    for (int tt = 0; tt < 2; ++tt) {
        int r0 = rbase + tt * 16;
        int rowa = r0 + (lane & 15);
        int rowc = min(rowa, NN - 1);                    // clamp for loads
        int kb = (lane >> 4) * 8;
        const float4* xp = (const float4*)(x + (size_t)rowc * ICH + kb);
        float4 xa[4][2];
#pragma unroll
        for (int s = 0; s < 4; ++s) {
            xa[s][0] = xp[s * 8];
            xa[s][1] = xp[s * 8 + 1];
        }
        floatx4 acc[3] = {{0.f, 0.f, 0.f, 0.f}, {0.f, 0.f, 0.f, 0.f}, {0.f, 0.f, 0.f, 0.f}};
#pragma unroll
        for (int s = 0; s < 4; ++s) {
            float f[8] = {xa[s][0].x, xa[s][0].y, xa[s][0].z, xa[s][0].w,
                          xa[s][1].x, xa[s][1].y, xa[s][1].z, xa[s][1].w};
            union { unsigned int u[4]; bf16x8 v; } ah, al;
#pragma unroll
            for (int p = 0; p < 4; ++p) {
                unsigned int h = pk_bf16(f[2 * p], f[2 * p + 1]);
                ah.u[p] = h;
                float l0 = f[2 * p] - __uint_as_float(h << 16);
                float l1 = f[2 * p + 1] - __uint_as_float(h & 0xFFFF0000u);
                al.u[p] = pk_bf16(l0, l1);
            }
#pragma unroll
            for (int n = 0; n < 3; ++n) {
                acc[n] = __builtin_amdgcn_mfma_f32_16x16x32_bf16(ah.v, whi[s][n], acc[n], 0, 0, 0);
                acc[n] = __builtin_amdgcn_mfma_f32_16x16x32_bf16(al.v, whi[s][n], acc[n], 0, 0, 0);
                acc[n] = __builtin_amdgcn_mfma_f32_16x16x32_bf16(ah.v, wlo[s][n], acc[n], 0, 0, 0);
            }
        }
        int rc0 = r0 + (lane >> 4) * 4;
        float dd[4];
#pragma unroll
        for (int r = 0; r < 4; ++r) dd[r] = (rc0 + r < NN) ? dis[rc0 + r] : 0.f;
#pragma unroll
        for (int n = 0; n < 3; ++n) {
            int col = n * 16 + (lane & 15);
            if (col < OCH) {
#pragma unroll
                for (int r = 0; r < 4; ++r) {
                    int row = rc0 + r;
                    if (row < NN) {
                        float val = acc[n][r] * dd[r];
                        int p8 = __builtin_amdgcn_cvt_pk_fp8_f32(val, val, 0, false);
                        y0[(size_t)row * YSTRIDE + col] = (unsigned char)(p8 & 0xFF);
                    }
                }
            }
        }
    }
}

// ---- hop 1: y1[i] = fp8( dis[i]^2 * (y0[i] + sum_in y0[src]) ); wave-aligned 5-lane groups ----
__global__ __launch_bounds__(256) void k_hop1(const int* __restrict__ rowptr, const int* __restrict__ csr,
                                              const float* __restrict__ dis, const unsigned char* __restrict__ y0,
                                              unsigned char* __restrict__ y1) {
    int t = threadIdx.x;
    int wave = t >> 6, lane = t & 63;
    int grp = lane / 5, q = lane - 5 * grp;
    int i = blockIdx.x * HOPNPB + wave * 12 + grp;
    if (grp >= 12 || i >= NN) return;
    int base = lane - q;                                 // wave-lane of group's q=0
    const uint2* yb = (const uint2*)y0;
    float acc[8];
#pragma unroll
    for (int j = 0; j < 8; ++j) acc[j] = 0.f;
    acc_fp8x8(yb[(size_t)i * YU2 + q], acc);
    row_gather(csr, rowptr[i], rowptr[i + 1], q, base, yb, acc);
    float d = dis[i], d2 = d * d;
#pragma unroll
    for (int j = 0; j < 8; ++j) acc[j] *= d2;
    ((uint2*)y1)[(size_t)i * YU2 + q] = pack_fp8x8(acc);
}

// ---- hop 2 gather + bias + log_softmax, fused; wave-aligned groups, shfl-only reduction.
//      Reduction reads lanes base+0..base+4 uniformly (R10 bug: started from own lane). ----
__global__ __launch_bounds__(256) void k_hop2f(const int* __restrict__ rowptr, const int* __restrict__ csr,
                                               const float* __restrict__ dis, const unsigned char* __restrict__ y1,
                                               const float* __restrict__ b, float* __restrict__ out) {
    int t = threadIdx.x;
    int wave = t >> 6, lane = t & 63;
    int grp = lane / 5, q = lane - 5 * grp;
    int g = blockIdx.x * HOPNPB + wave * 12 + grp;
    if (grp >= 12 || g >= NN) return;
    int base = lane - q;
    const uint2* yb = (const uint2*)y1;
    float acc[8];
#pragma unroll
    for (int j = 0; j < 8; ++j) acc[j] = 0.f;
    acc_fp8x8(yb[(size_t)g * YU2 + q], acc);
    row_gather(csr, rowptr[g], rowptr[g + 1], q, base, yb, acc);
    float d = dis[g];
    float l[8];
#pragma unroll
    for (int j = 0; j < 8; ++j) l[j] = d * acc[j] + b[8 * q + j];
    float m8 = l[0];
#pragma unroll
    for (int j = 1; j < 8; ++j) m8 = fmaxf(m8, l[j]);
    float gm = -1e30f;
#pragma unroll
    for (int j = 0; j < 5; ++j) gm = fmaxf(gm, __shfl(m8, base + j, 64));
    float s8 = 0.f;
#pragma unroll
    for (int j = 0; j < 8; ++j) s8 += __expf(l[j] - gm);
    float gs = 0.f;
#pragma unroll
    for (int j = 0; j < 5; ++j) gs += __shfl(s8, base + j, 64);
    float ls = __logf(gs) + gm;
    floatx4* orow = (floatx4*)(out + (size_t)g * OCH + 8 * q);
    floatx4 o0 = {l[0] - ls, l[1] - ls, l[2] - ls, l[3] - ls};
    floatx4 o1 = {l[4] - ls, l[5] - ls, l[6] - ls, l[7] - ls};
    __builtin_nontemporal_store(o0, orow);
    __builtin_nontemporal_store(o1, orow + 1);
}

extern "C" void kernel_launch(void* const* d_in, const int* in_sizes, int n_in,
                              void* d_out, int out_size, void* d_ws, size_t ws_size,
                              hipStream_t stream) {
    const float* x  = (const float*)d_in[0];
    const int*   ei = (const int*)d_in[1];   // (2, E) int32; [0]=src, [1]=dst
    const float* W  = (const float*)d_in[2];
    const float* b  = (const float*)d_in[3];
    float* out = (float*)d_out;

    char* ws = (char*)d_ws;
    int*           bcursor = (int*)(ws + 0);            // NB ints
    int*           rowptr  = (int*)(ws + 4096);         // NN+1 ints -> ends 404100
    float*         dis     = (float*)(ws + 409600);     // NN floats -> ends 809600
    unsigned int*  wbf     = (unsigned int*)(ws + 811008);   // 1536 x 16 B -> ends 835584
    unsigned int*  packed  = (unsigned int*)(ws + 843776);   // NB*CAP*4 = 14.41 MB (dead after k_csr)
    unsigned char* y0      = (unsigned char*)(ws + 843776);  // aliases packed, 4.0 MB
    unsigned char* y1      = (unsigned char*)(ws + 4849664); // aliases packed, 4.0 MB (ends 8849664)
    int*           csr     = (int*)(ws + 15261696);     // NE ints (12.8 MB) -> total ~28.06 MB

    hipMemsetAsync(bcursor, 0, NB * sizeof(int), stream);
    k_bin<<<NBIN, 512, 0, stream>>>(ei, bcursor, packed, W, wbf);
    k_csr<<<NB, 512, 0, stream>>>(bcursor, packed, rowptr, dis, csr);
    k_xw<<<XWBLK, 128, 0, stream>>>(x, wbf, dis, y0);
    k_hop1<<<HOPGRID, 256, 0, stream>>>(rowptr, csr, dis, y0, y1);
    k_hop2f<<<HOPGRID, 256, 0, stream>>>(rowptr, csr, dis, y1, b, out);
}

// Round 13
// 232.669 us; speedup vs baseline: 2.5662x; 1.0055x over previous
//
#include <hip/hip_runtime.h>
#include <hip/hip_fp16.h>
#include <math.h>

#define NN 100000
#define ICH 128
#define OCH 40
#define NE 3200000
#define BSH 8                          // bucket = dst >> 8 (256 nodes/bucket)
#define BNODES 256
#define BMASK 255
#define NB 391                         // ceil(100000/256)
#define CAP 9216                       // per-bucket capacity (mean 8192, sigma ~91)
#define TILE 4096
#define NBIN ((NE + TILE - 1) / TILE)  // 782
#define YSTRIDE 40                     // fp8 row: 40 B packed -> whole y array 4.0 MB ~ L2-resident
#define YU2 (YSTRIDE / 8)              // 5 uint2 per row
#define XWBLK 1563                     // ceil(NN/64) blocks of 128 threads (2 waves x 32 rows)
#define HOPNPB 24                      // hop kernels: 2 waves x 12 nodes (5 lanes/node, lanes 0-59)
#define HOPGRID ((NN + HOPNPB - 1) / HOPNPB)  // 4167 blocks -> fine-grain CU refill

typedef __attribute__((ext_vector_type(2))) float floatx2;
typedef __attribute__((ext_vector_type(4))) float floatx4;  // native vec for __builtin_nontemporal_store
typedef __attribute__((ext_vector_type(8))) short bf16x8;   // MFMA A/B fragment (4 VGPRs)

// v_cvt_pk_bf16_f32: pack 2 f32 -> 2 bf16 in one u32 (lo16 = src0), RNE. No builtin on gfx950.
__device__ __forceinline__ unsigned int pk_bf16(float a, float b) {
    unsigned int r;
    asm("v_cvt_pk_bf16_f32 %0, %1, %2" : "=v"(r) : "v"(a), "v"(b));
    return r;
}

// decode 8 fp8 (uint2) -> acc[8] +=
__device__ __forceinline__ void acc_fp8x8(const uint2 u, float* acc) {
    floatx2 p0 = __builtin_amdgcn_cvt_pk_f32_fp8((int)u.x, false);
    floatx2 p1 = __builtin_amdgcn_cvt_pk_f32_fp8((int)u.x, true);
    floatx2 p2 = __builtin_amdgcn_cvt_pk_f32_fp8((int)u.y, false);
    floatx2 p3 = __builtin_amdgcn_cvt_pk_f32_fp8((int)u.y, true);
    acc[0] += p0.x; acc[1] += p0.y; acc[2] += p1.x; acc[3] += p1.y;
    acc[4] += p2.x; acc[5] += p2.y; acc[6] += p3.x; acc[7] += p3.y;
}

// encode 8 f32 -> uint2 of fp8
__device__ __forceinline__ uint2 pack_fp8x8(const float* v) {
    int lo = 0, hi = 0;
    lo = __builtin_amdgcn_cvt_pk_fp8_f32(v[0], v[1], lo, false);
    lo = __builtin_amdgcn_cvt_pk_fp8_f32(v[2], v[3], lo, true);
    hi = __builtin_amdgcn_cvt_pk_fp8_f32(v[4], v[5], hi, false);
    hi = __builtin_amdgcn_cvt_pk_fp8_f32(v[6], v[7], hi, true);
    return make_uint2((unsigned int)lo, (unsigned int)hi);
}

// load 8 csr indices for a 5-lane node group: lanes q<4 load uint2 (one VMEM instr for the
// group instead of 8), then redistribute via shfl. base = wave-lane of the group's q=0 lane.
__device__ __forceinline__ void grp_csr8(const int* __restrict__ csr, int k, int q, int base, int* s) {
    uint2 c = make_uint2(0u, 0u);
    if (q < 4) c = *(const uint2*)(csr + k + 2 * q);
#pragma unroll
    for (int j = 0; j < 8; ++j)
        s[j] = __shfl((j & 1) ? (int)c.y : (int)c.x, base + (j >> 1), 64);
}

// gather-accumulate over one CSR row: wave-local group csr sharing + 8-deep gather pipeline.
// Tail (<8 edges) is a PARALLEL masked batch (index-clamped gathers, acc masked to j<r) --
// no serial load->acc chain.
__device__ __forceinline__ void row_gather(const int* __restrict__ csr, int kb, int ke, int q, int base,
                                           const uint2* __restrict__ yb, float* acc) {
    int k = kb;
    if (k + 8 <= ke) {
        int s[8];
        uint2 v[8];
        grp_csr8(csr, k, q, base, s);
#pragma unroll
        for (int j = 0; j < 8; ++j) v[j] = yb[(size_t)s[j] * YU2 + q];
        k += 8;
        for (; k + 8 <= ke; k += 8) {
            int s2[8];
            uint2 w[8];
            grp_csr8(csr, k, q, base, s2);
#pragma unroll
            for (int j = 0; j < 8; ++j) w[j] = yb[(size_t)s2[j] * YU2 + q];  // in flight during acc below
#pragma unroll
            for (int j = 0; j < 8; ++j) acc_fp8x8(v[j], acc);
#pragma unroll
            for (int j = 0; j < 8; ++j) v[j] = w[j];
        }
        int r = ke - k;                                  // 0..7 remainder
        if (r > 0) {
            int s2[8];
            uint2 w[8];
#pragma unroll
            for (int j = 0; j < 8; ++j) s2[j] = csr[k + min(j, r - 1)];  // clamped: stays in-bounds
#pragma unroll
            for (int j = 0; j < 8; ++j) w[j] = yb[(size_t)s2[j] * YU2 + q];
#pragma unroll
            for (int j = 0; j < 8; ++j) acc_fp8x8(v[j], acc);
#pragma unroll
            for (int j = 0; j < 8; ++j)
                if (j < r) acc_fp8x8(w[j], acc);
        } else {
#pragma unroll
            for (int j = 0; j < 8; ++j) acc_fp8x8(v[j], acc);
        }
    } else {
        int r = ke - k;
        if (r > 0) {
            int s[8];
            uint2 v[8];
#pragma unroll
            for (int j = 0; j < 8; ++j) s[j] = csr[k + min(j, r - 1)];
#pragma unroll
            for (int j = 0; j < 8; ++j) v[j] = yb[(size_t)s[j] * YU2 + q];
#pragma unroll
            for (int j = 0; j < 8; ++j)
                if (j < r) acc_fp8x8(v[j], acc);
        }
    }
}

// ---- phase 1: bin edges by dst-bucket; block 0 additionally emits the W fragment shuffle ----
// wbf layout: [hs(2)][s(4)][n(3)][lane(64)] x short8 ; entry e holds W[s*32+(lane>>4)*8+j][n*16+(lane&15)]
__global__ __launch_bounds__(512) void k_bin(const int* __restrict__ ei, int* __restrict__ bcursor,
                                             unsigned int* __restrict__ packed,
                                             const float* __restrict__ W, unsigned int* __restrict__ wbf) {
    __shared__ unsigned int entries[TILE];
    __shared__ unsigned short bid[TILE];
    __shared__ int hist[512], base[512], gbase[512], cur[512];
    int t = threadIdx.x;
    int tile0 = blockIdx.x * TILE;
    int tcnt = min(TILE, NE - tile0);
    hist[t] = 0;
    __syncthreads();
    int src[8], dst[8];
#pragma unroll
    for (int i = 0; i < 8; ++i) {
        int l = t + i * 512;
        if (l < tcnt) {
            int e = tile0 + l;
            src[i] = ei[e];
            dst[i] = ei[NE + e];
            atomicAdd(&hist[dst[i] >> BSH], 1);
        } else dst[i] = -1;
    }
    __syncthreads();
    int own = hist[t];
    base[t] = own;
    __syncthreads();
    for (int off = 1; off < 512; off <<= 1) {
        int v = (t >= off) ? base[t - off] : 0;
        __syncthreads();
        base[t] += v;
        __syncthreads();
    }
    int excl = base[t] - own;
    __syncthreads();
    base[t] = excl;
    cur[t] = excl;
    if (t < NB && own > 0) gbase[t] = atomicAdd(&bcursor[t], own);
    __syncthreads();
#pragma unroll
    for (int i = 0; i < 8; ++i) {
        if (dst[i] >= 0) {
            int bb = dst[i] >> BSH;
            int pos = atomicAdd(&cur[bb], 1);
            entries[pos] = ((unsigned int)(dst[i] & BMASK) << 17) | (unsigned int)src[i];
            bid[pos] = (unsigned short)bb;
        }
    }
    __syncthreads();
    for (int l = t; l < tcnt; l += 512) {
        int bb = bid[l];
        packed[(size_t)bb * CAP + gbase[bb] + (l - base[bb])] = entries[l];
    }
    // one-time W shuffle (hi+lo bf16 split), done by block 0's tail, hidden under other blocks
    if (blockIdx.x == 0) {
        for (int e = t; e < 1536; e += 512) {
            int hs = e / 768;
            int rem = e - hs * 768;
            int ss = rem / 192;
            int rem2 = rem - ss * 192;
            int n = rem2 >> 6;
            int lane = rem2 & 63;
            int kbase = ss * 32 + (lane >> 4) * 8;
            int col = n * 16 + (lane & 15);
            unsigned int u4[4];
#pragma unroll
            for (int p = 0; p < 4; ++p) {
                float f0 = (col < OCH) ? W[(size_t)(kbase + 2 * p) * OCH + col] : 0.f;
                float f1 = (col < OCH) ? W[(size_t)(kbase + 2 * p + 1) * OCH + col] : 0.f;
                unsigned int h = pk_bf16(f0, f1);
                if (hs == 0) {
                    u4[p] = h;
                } else {
                    float l0 = f0 - __uint_as_float(h << 16);
                    float l1 = f1 - __uint_as_float(h & 0xFFFF0000u);
                    u4[p] = pk_bf16(l0, l1);
                }
            }
            ((uint4*)wbf)[e] = make_uint4(u4[0], u4[1], u4[2], u4[3]);
        }
    }
}

// ---- phase 2: per-bucket CSR build; self-computed cbase (no k_bscan), no LDS edge staging ----
__global__ __launch_bounds__(512) void k_csr(const int* __restrict__ bcursor,
                                             const unsigned int* __restrict__ packed,
                                             int* __restrict__ rowptr, float* __restrict__ dis,
                                             int* __restrict__ csr) {
    __shared__ int hist[BNODES], cur[BNODES], ps[BNODES], sred[512];
    int b = blockIdx.x;
    int t = threadIdx.x;
    // cbase = sum_{j<b} bcursor[j]  (bcursor is 1.5 KB, L2-hot)
    int part = 0;
    for (int j = t; j < b; j += 512) part += bcursor[j];
    sred[t] = part;
    if (t < BNODES) hist[t] = 0;
    __syncthreads();
    for (int off = 256; off > 0; off >>= 1) {
        if (t < off) sred[t] += sred[t + off];
        __syncthreads();
    }
    int cbase = sred[0];
    int cnt = bcursor[b];
    int node0 = b << BSH;
    int nn = min(BNODES, NN - node0);
    const unsigned int* pk = packed + (size_t)b * CAP;
    for (int l = t; l < cnt; l += 512) atomicAdd(&hist[pk[l] >> 17], 1);
    __syncthreads();
    if (t < BNODES) ps[t] = hist[t];
    __syncthreads();
    for (int off = 1; off < BNODES; off <<= 1) {
        int u = (t >= off && t < BNODES) ? ps[t - off] : 0;
        __syncthreads();
        if (t < BNODES) ps[t] += u;
        __syncthreads();
    }
    if (t < BNODES) {
        int excl = ps[t] - hist[t];
        cur[t] = excl;
        if (t < nn) {
            rowptr[node0 + t] = cbase + excl;
            dis[node0 + t] = rsqrtf((float)hist[t] + 1.0f);
        }
    }
    if (b == 0 && t == 0) rowptr[NN] = NE;
    __syncthreads();
    for (int l = t; l < cnt; l += 512) {
        unsigned int e = pk[l];               // second read: bucket slab is 32 KB, L2-resident
        int pos = atomicAdd(&cur[e >> 17], 1);
        csr[cbase + pos] = (int)(e & 0x1FFFF);
    }
}

// ---- y0 = fp8( dis * (x @ W) ) via MFMA bf16 with 3-term split (f32-accurate) ----
__global__ __launch_bounds__(128) void k_xw(const float* __restrict__ x, const unsigned int* __restrict__ wbf,
                                            const float* __restrict__ dis, unsigned char* __restrict__ y0) {
    int t = threadIdx.x;
    int wid = t >> 6, lane = t & 63;
    const bf16x8* wf = (const bf16x8*)wbf;
    bf16x8 whi[4][3], wlo[4][3];
#pragma unroll
    for (int s = 0; s < 4; ++s)
#pragma unroll
        for (int n = 0; n < 3; ++n) {
            whi[s][n] = wf[(s * 3 + n) * 64 + lane];
            wlo[s][n] = wf[768 + (s * 3 + n) * 64 + lane];
        }
    int rbase = blockIdx.x * 64 + wid * 32;
#pragma unroll
    for (int tt = 0; tt < 2; ++tt) {
        int r0 = rbase + tt * 16;
        int rowa = r0 + (lane & 15);
        int rowc = min(rowa, NN - 1);                    // clamp for loads
        int kb = (lane >> 4) * 8;
        const float4* xp = (const float4*)(x + (size_t)rowc * ICH + kb);
        float4 xa[4][2];
#pragma unroll
        for (int s = 0; s < 4; ++s) {
            xa[s][0] = xp[s * 8];
            xa[s][1] = xp[s * 8 + 1];
        }
        floatx4 acc[3] = {{0.f, 0.f, 0.f, 0.f}, {0.f, 0.f, 0.f, 0.f}, {0.f, 0.f, 0.f, 0.f}};
#pragma unroll
        for (int s = 0; s < 4; ++s) {
            float f[8] = {xa[s][0].x, xa[s][0].y, xa[s][0].z, xa[s][0].w,
                          xa[s][1].x, xa[s][1].y, xa[s][1].z, xa[s][1].w};
            union { unsigned int u[4]; bf16x8 v; } ah, al;
#pragma unroll
            for (int p = 0; p < 4; ++p) {
                unsigned int h = pk_bf16(f[2 * p], f[2 * p + 1]);
                ah.u[p] = h;
                float l0 = f[2 * p] - __uint_as_float(h << 16);
                float l1 = f[2 * p + 1] - __uint_as_float(h & 0xFFFF0000u);
                al.u[p] = pk_bf16(l0, l1);
            }
#pragma unroll
            for (int n = 0; n < 3; ++n) {
                acc[n] = __builtin_amdgcn_mfma_f32_16x16x32_bf16(ah.v, whi[s][n], acc[n], 0, 0, 0);
                acc[n] = __builtin_amdgcn_mfma_f32_16x16x32_bf16(al.v, whi[s][n], acc[n], 0, 0, 0);
                acc[n] = __builtin_amdgcn_mfma_f32_16x16x32_bf16(ah.v, wlo[s][n], acc[n], 0, 0, 0);
            }
        }
        int rc0 = r0 + (lane >> 4) * 4;
        float dd[4];
#pragma unroll
        for (int r = 0; r < 4; ++r) dd[r] = (rc0 + r < NN) ? dis[rc0 + r] : 0.f;
#pragma unroll
        for (int n = 0; n < 3; ++n) {
            int col = n * 16 + (lane & 15);
            if (col < OCH) {
#pragma unroll
                for (int r = 0; r < 4; ++r) {
                    int row = rc0 + r;
                    if (row < NN) {
                        float val = acc[n][r] * dd[r];
                        int p8 = __builtin_amdgcn_cvt_pk_fp8_f32(val, val, 0, false);
                        y0[(size_t)row * YSTRIDE + col] = (unsigned char)(p8 & 0xFF);
                    }
                }
            }
        }
    }
}

// ---- hop 1: y1[i] = fp8( dis[i]^2 * (y0[i] + sum_in y0[src]) ); wave-aligned 5-lane groups ----
__global__ __launch_bounds__(128) void k_hop1(const int* __restrict__ rowptr, const int* __restrict__ csr,
                                              const float* __restrict__ dis, const unsigned char* __restrict__ y0,
                                              unsigned char* __restrict__ y1) {
    int t = threadIdx.x;
    int wave = t >> 6, lane = t & 63;
    int grp = lane / 5, q = lane - 5 * grp;
    int i = blockIdx.x * HOPNPB + wave * 12 + grp;
    if (grp >= 12 || i >= NN) return;
    int base = lane - q;                                 // wave-lane of group's q=0
    const uint2* yb = (const uint2*)y0;
    float acc[8];
#pragma unroll
    for (int j = 0; j < 8; ++j) acc[j] = 0.f;
    acc_fp8x8(yb[(size_t)i * YU2 + q], acc);
    row_gather(csr, rowptr[i], rowptr[i + 1], q, base, yb, acc);
    float d = dis[i], d2 = d * d;
#pragma unroll
    for (int j = 0; j < 8; ++j) acc[j] *= d2;
    ((uint2*)y1)[(size_t)i * YU2 + q] = pack_fp8x8(acc);
}

// ---- hop 2 gather + bias + log_softmax, fused; wave-aligned groups, shfl-only reduction
//      over lanes base+0..base+4 uniformly ----
__global__ __launch_bounds__(128) void k_hop2f(const int* __restrict__ rowptr, const int* __restrict__ csr,
                                               const float* __restrict__ dis, const unsigned char* __restrict__ y1,
                                               const float* __restrict__ b, float* __restrict__ out) {
    int t = threadIdx.x;
    int wave = t >> 6, lane = t & 63;
    int grp = lane / 5, q = lane - 5 * grp;
    int g = blockIdx.x * HOPNPB + wave * 12 + grp;
    if (grp >= 12 || g >= NN) return;
    int base = lane - q;
    const uint2* yb = (const uint2*)y1;
    float acc[8];
#pragma unroll
    for (int j = 0; j < 8; ++j) acc[j] = 0.f;
    acc_fp8x8(yb[(size_t)g * YU2 + q], acc);
    row_gather(csr, rowptr[g], rowptr[g + 1], q, base, yb, acc);
    float d = dis[g];
    float l[8];
#pragma unroll
    for (int j = 0; j < 8; ++j) l[j] = d * acc[j] + b[8 * q + j];
    float m8 = l[0];
#pragma unroll
    for (int j = 1; j < 8; ++j) m8 = fmaxf(m8, l[j]);
    float gm = -1e30f;
#pragma unroll
    for (int j = 0; j < 5; ++j) gm = fmaxf(gm, __shfl(m8, base + j, 64));
    float s8 = 0.f;
#pragma unroll
    for (int j = 0; j < 8; ++j) s8 += __expf(l[j] - gm);
    float gs = 0.f;
#pragma unroll
    for (int j = 0; j < 5; ++j) gs += __shfl(s8, base + j, 64);
    float ls = __logf(gs) + gm;
    floatx4* orow = (floatx4*)(out + (size_t)g * OCH + 8 * q);
    floatx4 o0 = {l[0] - ls, l[1] - ls, l[2] - ls, l[3] - ls};
    floatx4 o1 = {l[4] - ls, l[5] - ls, l[6] - ls, l[7] - ls};
    __builtin_nontemporal_store(o0, orow);
    __builtin_nontemporal_store(o1, orow + 1);
}

extern "C" void kernel_launch(void* const* d_in, const int* in_sizes, int n_in,
                              void* d_out, int out_size, void* d_ws, size_t ws_size,
                              hipStream_t stream) {
    const float* x  = (const float*)d_in[0];
    const int*   ei = (const int*)d_in[1];   // (2, E) int32; [0]=src, [1]=dst
    const float* W  = (const float*)d_in[2];
    const float* b  = (const float*)d_in[3];
    float* out = (float*)d_out;

    char* ws = (char*)d_ws;
    int*           bcursor = (int*)(ws + 0);            // NB ints
    int*           rowptr  = (int*)(ws + 4096);         // NN+1 ints -> ends 404100
    float*         dis     = (float*)(ws + 409600);     // NN floats -> ends 809600
    unsigned int*  wbf     = (unsigned int*)(ws + 811008);   // 1536 x 16 B -> ends 835584
    unsigned int*  packed  = (unsigned int*)(ws + 843776);   // NB*CAP*4 = 14.41 MB (dead after k_csr)
    unsigned char* y0      = (unsigned char*)(ws + 843776);  // aliases packed, 4.0 MB
    unsigned char* y1      = (unsigned char*)(ws + 4849664); // aliases packed, 4.0 MB (ends 8849664)
    int*           csr     = (int*)(ws + 15261696);     // NE ints (12.8 MB) -> total ~28.06 MB

    hipMemsetAsync(bcursor, 0, NB * sizeof(int), stream);
    k_bin<<<NBIN, 512, 0, stream>>>(ei, bcursor, packed, W, wbf);
    k_csr<<<NB, 512, 0, stream>>>(bcursor, packed, rowptr, dis, csr);
    k_xw<<<XWBLK, 128, 0, stream>>>(x, wbf, dis, y0);
    k_hop1<<<HOPGRID, 128, 0, stream>>>(rowptr, csr, dis, y0, y1);
    k_hop2f<<<HOPGRID, 128, 0, stream>>>(rowptr, csr, dis, y1, b, out);
}